// Round 14
// baseline (140.438 us; speedup 1.0000x reference)
//
#include <hip/hip_runtime.h>

// Fused deformable-conv net — 2 images per 448-thread (7-wave) block.
// Lane packing 392/448 = 87.5% vs champion's 196/256 = 76.6% (1.14x fewer
// issue slots), while avoiding every identified killer of past packings:
//  - staging: each image staged exactly once (aligned 2-per-block), FETCH
//    stays ~6.8 MB (r8's misaligned 3-image scheme re-fetched 2.2x)
//  - weights in LDS (r7 recipe; r6's global weights + SGPR pressure)
//  - only wave 3 straddles images -> one segmented butterfly; all other
//    waves identical to champion. No atomics, no division.
// Inner body frozen verbatim from r13 champion (64 VGPR, 92-95% VALUBusy):
// k-outer/p-inner acc[4][8], direct xs[int] indexing, med3 clamps,
// factored bilinear, o-outer FC, scalar fp32 only.

#define HH 28
#define WW 28
#define WP 30
#define NPOS 784
#define NPOOL 1568
#define CELLS 196
#define IPB 2
#define NTHR 448

__global__ __launch_bounds__(NTHR) void deform_net_kernel(
    const float* __restrict__ x,       // (B,1,28,28)
    const float* __restrict__ w_off,   // (18,1,3,3)
    const float* __restrict__ b_off,   // (18,)
    const float* __restrict__ w_conv,  // (8,1,3,3)
    const float* __restrict__ w_fc,    // (10,1568)
    const float* __restrict__ b_fc,    // (10,)
    float* __restrict__ out,           // (B,10)
    int B)
{
    __shared__ float xs[IPB * 900];    // 2 padded images, 7.2 KB
    __shared__ float wo_s[162];        // w_off
    __shared__ float bo_s[18];         // b_off
    __shared__ float wc_s[72];         // w_conv
    __shared__ float red[IPB][7][10];  // [img][wave][class]

    const int tid      = threadIdx.x;
    const int img_base = blockIdx.x * IPB;

    if (tid < 162) wo_s[tid] = w_off[tid];
    if (tid < 18)  bo_s[tid] = b_off[tid];
    if (tid < 72)  wc_s[tid] = w_conv[tid];

    // Stage 2 zero-padded 30x30 images, each exactly once.
    for (int i = tid; i < IPB * 900; i += NTHR) {
        int s = (i >= 900) ? 1 : 0;
        int j = i - s * 900;
        int img = img_base + s;
        float v = 0.f;
        if (img < B) {
            int r = j / WP, c = j - r * WP;
            if (r >= 1 && r <= HH && c >= 1 && c <= WW)
                v = x[(size_t)img * NPOS + (r - 1) * WW + (c - 1)];
        }
        xs[i] = v;
    }
    __syncthreads();

    const int img_l = (tid >= CELLS) ? 1 : 0;   // 0 or 1
    const int cell  = tid - img_l * CELLS;       // valid when tid < 392
    const int xb0   = img_l * 900;

    float fc[10];
    #pragma unroll
    for (int c = 0; c < 10; c++) fc[c] = 0.f;

    if (tid < IPB * CELLS && img_base + img_l < B) {
        const int ph = cell / 14, pw = cell % 14;  // pool cell coords
        const int h0 = 2 * ph, w0 = 2 * pw;        // top-left output position

        // 4x4 padded-image neighborhood covering all 4 positions' 3x3 taps.
        float nb[16];
        #pragma unroll
        for (int i = 0; i < 4; i++)
            #pragma unroll
            for (int j = 0; j < 4; j++)
                nb[i * 4 + j] = xs[xb0 + (h0 + i) * WP + (w0 + j)];

        float acc[4][8];
        #pragma unroll
        for (int p = 0; p < 4; p++)
            #pragma unroll
            for (int o = 0; o < 8; o++) acc[p][o] = 0.f;

        #pragma unroll
        for (int k = 0; k < 9; k++) {          // deform tap
            const int kx = k / 3, ky = k % 3;
            #pragma unroll
            for (int p = 0; p < 4; p++) {      // position within pool cell
                const int dh = p >> 1, dw = p & 1;

                // offset channels k (x) and k+9 (y): 3x3 conv at (h0+dh, w0+dw)
                float offx = bo_s[k], offy = bo_s[k + 9];
                #pragma unroll
                for (int t = 0; t < 9; t++) {
                    float nv = nb[(dh + t / 3) * 4 + (dw + t % 3)];
                    offx = fmaf(wo_s[k * 9 + t],       nv, offx);
                    offy = fmaf(wo_s[(k + 9) * 9 + t], nv, offy);
                }

                // sample coords in padded frame: p0=(h+1,w+1), pn=(kx-1,ky-1)
                float p_x = (float)(h0 + dh + kx) + offx;
                float p_y = (float)(w0 + dw + ky) + offy;

                float q0x = floorf(p_x), q0y = floorf(p_y);
                float qltx = __builtin_amdgcn_fmed3f(q0x,       0.f, 29.f);
                float qlty = __builtin_amdgcn_fmed3f(q0y,       0.f, 29.f);
                float qrbx = __builtin_amdgcn_fmed3f(q0x + 1.f, 0.f, 29.f);
                float qrby = __builtin_amdgcn_fmed3f(q0y + 1.f, 0.f, 29.f);
                float px   = __builtin_amdgcn_fmed3f(p_x,       0.f, 29.f);
                float py   = __builtin_amdgcn_fmed3f(p_y,       0.f, 29.f);

                float gltx = 1.f + (qltx - px);
                float glty = 1.f + (qlty - py);
                float grbx = 1.f - (qrbx - px);
                float grby = 1.f - (qrby - py);

                int ilx = (int)qltx, ily = (int)qlty;
                int irx = (int)qrbx, iry = (int)qrby;

                float xlt = xs[xb0 + ilx * WP + ily];
                float xrb = xs[xb0 + irx * WP + iry];
                float xlb = xs[xb0 + ilx * WP + iry];
                float xrt = xs[xb0 + irx * WP + ily];

                // factored bilinear combine (same clip semantics)
                float s = gltx * (glty * xlt + grby * xlb)
                        + grbx * (glty * xrt + grby * xrb);

                #pragma unroll
                for (int o = 0; o < 8; o++)
                    acc[p][o] = fmaf(wc_s[o * 9 + k], s, acc[p][o]);
            }
        }

        // relu + 2x2 maxpool in registers, then FC partial sums (o-outer).
        #pragma unroll
        for (int o = 0; o < 8; o++) {
            float m = fmaxf(fmaxf(acc[0][o], acc[1][o]),
                            fmaxf(acc[2][o], acc[3][o]));
            m = fmaxf(m, 0.f);
            const float* wrow = w_fc + o * CELLS + cell;
            #pragma unroll
            for (int c = 0; c < 10; c++)
                fc[c] = fmaf(m, wrow[c * NPOOL], fc[c]);
        }
        if (cell == 0) {          // once per image (tid 0 and tid 196)
            #pragma unroll
            for (int c = 0; c < 10; c++) fc[c] += b_fc[c];
        }
    }

    // Reduction. Waves 0-2: img0 only. Wave 3: straddles (lanes 0-3 img0,
    // 4-63 img1) -> segmented dual butterfly. Waves 4-6: img1 only.
    const int lane = tid & 63;
    const int w    = tid >> 6;

    if (w == 3) {
        const bool in0 = (img_l == 0);
        #pragma unroll
        for (int c = 0; c < 10; c++) {
            float v0 = in0 ? fc[c] : 0.f;
            float v1 = fc[c] - v0;
            #pragma unroll
            for (int sh = 32; sh > 0; sh >>= 1) {
                v0 += __shfl_down(v0, sh, 64);
                v1 += __shfl_down(v1, sh, 64);
            }
            if (lane == 0) {
                red[0][3][c] = v0;
                red[1][3][c] = v1;
            }
        }
    } else {
        const int seg = (w < 3) ? 0 : 1;
        #pragma unroll
        for (int c = 0; c < 10; c++) {
            float v = fc[c];
            #pragma unroll
            for (int sh = 32; sh > 0; sh >>= 1) v += __shfl_down(v, sh, 64);
            if (lane == 0) red[seg][w][c] = v;
        }
    }
    __syncthreads();

    // Final: 20 threads, one (image, class) each. img0 <- waves 0..3,
    // img1 <- waves 3..6.
    if (tid < IPB * 10) {
        int il = tid / 10, c = tid - il * 10;
        int img = img_base + il;
        if (img < B) {
            int wlo = il ? 3 : 0;
            float a = red[il][wlo][c] + red[il][wlo + 1][c]
                    + red[il][wlo + 2][c] + red[il][wlo + 3][c];
            out[img * 10 + c] = a;
        }
    }
}

extern "C" void kernel_launch(void* const* d_in, const int* in_sizes, int n_in,
                              void* d_out, int out_size, void* d_ws, size_t ws_size,
                              hipStream_t stream) {
    const float* x      = (const float*)d_in[0];
    const float* w_off  = (const float*)d_in[1];
    const float* b_off  = (const float*)d_in[2];
    const float* w_conv = (const float*)d_in[3];
    const float* w_fc   = (const float*)d_in[4];
    const float* b_fc   = (const float*)d_in[5];
    float* out = (float*)d_out;

    const int B = in_sizes[0] / NPOS;
    const int grid = (B + IPB - 1) / IPB;
    deform_net_kernel<<<grid, NTHR, 0, stream>>>(x, w_off, b_off, w_conv,
                                                 w_fc, b_fc, out, B);
}